// Round 1
// baseline (421.465 us; speedup 1.0000x reference)
//
#include <hip/hip_runtime.h>
#include <math.h>

#define NEG_SLOPE 0.2f

typedef __attribute__((ext_vector_type(8))) short short8;
typedef __attribute__((ext_vector_type(2))) float f32x2;
typedef __attribute__((ext_vector_type(4))) float f32x4;
typedef __attribute__((ext_vector_type(16))) float f32x16;

__device__ __forceinline__ float eluf(float x) { return x > 0.f ? x : expm1f(x); }
__device__ __forceinline__ unsigned short f2b(float f) {
  unsigned int u = __float_as_uint(f);
  u += 0x7FFFu + ((u >> 16) & 1u);  // RNE
  return (unsigned short)(u >> 16);
}
__device__ __forceinline__ float b2f(unsigned short h) {
  return __uint_as_float(((unsigned int)h) << 16);
}

// ---------------- weights: build extended Bt for both layers.
// B1t[288][128]: rows 0..255 = W1^T bf16; rows 256..263 = P_el (W1 . al1),
// rows 264..271 = P_er, rows 272..287 = 0.   B2t[288][256] likewise.
__global__ __launch_bounds__(256) void cast_w_both(const float* __restrict__ W1,
                                                   unsigned short* __restrict__ B1t,
                                                   const float* __restrict__ W2,
                                                   unsigned short* __restrict__ B2t,
                                                   const float* __restrict__ al1,
                                                   const float* __restrict__ ar1,
                                                   const float* __restrict__ al2,
                                                   const float* __restrict__ ar2) {
  int id = blockIdx.x * 256 + threadIdx.x;
  if (id < 128 * 256) {
    int k = id >> 8, n = id & 255;
    B1t[(size_t)n * 128 + k] = f2b(W1[id]);
    return;
  }
  id -= 128 * 256;
  if (id < 256 * 256) {
    int k = id >> 8, n = id & 255;
    B2t[(size_t)n * 256 + k] = f2b(W2[id]);
    return;
  }
  id -= 256 * 256;
  if (id < 128 * 16) {
    int k = id >> 4, h2 = id & 15;
    int h = h2 & 7;
    const float* av = (h2 < 8) ? al1 : ar1;
    float acc = 0.f;
    for (int d = 0; d < 32; ++d) acc = fmaf(W1[(size_t)k * 256 + h * 32 + d], av[h * 32 + d], acc);
    B1t[(size_t)(256 + h2) * 128 + k] = f2b(acc);
    return;
  }
  id -= 128 * 16;
  if (id < 256 * 16) {
    int k = id >> 4, h2 = id & 15;
    int h = h2 & 7;
    const float* av = (h2 < 8) ? al2 : ar2;
    float acc = 0.f;
    for (int d = 0; d < 32; ++d) acc = fmaf(W2[(size_t)k * 256 + h * 32 + d], av[h * 32 + d], acc);
    B2t[(size_t)(256 + h2) * 256 + k] = f2b(acc);
    return;
  }
  id -= 256 * 16;
  if (id < 16 * 128) {
    int k = id & 127, rr = 272 + (id >> 7);
    B1t[(size_t)rr * 128 + k] = 0;
    return;
  }
  id -= 16 * 128;
  if (id < 16 * 256) {
    int k = id & 255, rr = 272 + (id >> 8);
    B2t[(size_t)rr * 256 + k] = 0;
  }
}

// ---------------- GEMM: Cq[M][256] (fp8 e4m3) = A[M][K] @ B  (Bt[288][K] bf16).
// BM=64 x BN=256(+32 el/er cols), BK=32, 4 waves 2x2, 32x32x16 MFMA.
#define GBM 64
#define GBK 32
#define GLDK 36
__global__ __launch_bounds__(256) void gemm_bf16_v4(const void* __restrict__ Araw, int a_fp32,
                                                    const unsigned short* __restrict__ Bt,
                                                    unsigned char* __restrict__ Cq,
                                                    float* __restrict__ el, float* __restrict__ er,
                                                    int M, int K) {
  __shared__ unsigned short As[GBM][GLDK];
  __shared__ unsigned short Bs[288][GLDK];
  const int tid = threadIdx.x;
  const int wave = tid >> 6, lane = tid & 63;
  const int wm = wave >> 1, wn = wave & 1;
  const int l32 = lane & 31, lhalf = lane >> 5;
  const int row0 = blockIdx.x * GBM;

  f32x16 acc[4] = {};
  f32x16 acc4 = {};

  const int ar = tid >> 2;
  const int ac = (tid & 3) * 8;
  const bool arow_ok = (row0 + ar) < M;

  for (int kk = 0; kk < K; kk += GBK) {
    short8 av = {};
    if (arow_ok) {
      if (a_fp32) {
        const float* p = (const float*)Araw + (size_t)(row0 + ar) * K + kk + ac;
        float4 lo = *(const float4*)p;
        float4 hi = *(const float4*)(p + 4);
        av[0] = (short)f2b(lo.x); av[1] = (short)f2b(lo.y);
        av[2] = (short)f2b(lo.z); av[3] = (short)f2b(lo.w);
        av[4] = (short)f2b(hi.x); av[5] = (short)f2b(hi.y);
        av[6] = (short)f2b(hi.z); av[7] = (short)f2b(hi.w);
      } else {
        av = *(const short8*)((const unsigned short*)Araw + (size_t)(row0 + ar) * K + kk + ac);
      }
    }
    *(short8*)&As[ar][ac] = av;
    {
      const unsigned short* bp = Bt + (size_t)tid * K + kk;
      short8 b0 = *(const short8*)(bp + 0);
      short8 b1 = *(const short8*)(bp + 8);
      short8 b2 = *(const short8*)(bp + 16);
      short8 b3 = *(const short8*)(bp + 24);
      *(short8*)&Bs[tid][0] = b0;
      *(short8*)&Bs[tid][8] = b1;
      *(short8*)&Bs[tid][16] = b2;
      *(short8*)&Bs[tid][24] = b3;
    }
    if (tid < 32) {
      const unsigned short* bp = Bt + (size_t)(256 + tid) * K + kk;
      short8 b0 = *(const short8*)(bp + 0);
      short8 b1 = *(const short8*)(bp + 8);
      short8 b2 = *(const short8*)(bp + 16);
      short8 b3 = *(const short8*)(bp + 24);
      *(short8*)&Bs[256 + tid][0] = b0;
      *(short8*)&Bs[256 + tid][8] = b1;
      *(short8*)&Bs[256 + tid][16] = b2;
      *(short8*)&Bs[256 + tid][24] = b3;
    }
    __syncthreads();
#pragma unroll
    for (int s = 0; s < 2; ++s) {
      short8 af = *(short8*)&As[wm * 32 + l32][s * 16 + lhalf * 8];
#pragma unroll
      for (int t = 0; t < 4; ++t) {
        short8 bf = *(short8*)&Bs[wn * 128 + t * 32 + l32][s * 16 + lhalf * 8];
        acc[t] = __builtin_amdgcn_mfma_f32_32x32x16_bf16(af, bf, acc[t], 0, 0, 0);
      }
      if (wn == 1) {
        short8 bf = *(short8*)&Bs[256 + l32][s * 16 + lhalf * 8];
        acc4 = __builtin_amdgcn_mfma_f32_32x32x16_bf16(af, bf, acc4, 0, 0, 0);
      }
    }
    __syncthreads();
  }

#pragma unroll
  for (int t = 0; t < 4; ++t) {
    int col = wn * 128 + t * 32 + l32;
#pragma unroll
    for (int reg = 0; reg < 16; ++reg) {
      int row = wm * 32 + (reg & 3) + 8 * (reg >> 2) + 4 * lhalf;
      int r = row0 + row;
      if (r < M) {
        int pk = __builtin_amdgcn_cvt_pk_fp8_f32(acc[t][reg], acc[t][reg], 0, false);
        Cq[(size_t)r * 256 + col] = (unsigned char)(pk & 0xFF);
      }
    }
  }
  if (wn == 1 && l32 < 16) {
#pragma unroll
    for (int reg = 0; reg < 16; ++reg) {
      int row = wm * 32 + (reg & 3) + 8 * (reg >> 2) + 4 * lhalf;
      int r = row0 + row;
      if (r < M) {
        if (l32 < 8) el[r * 8 + l32] = acc4[reg];
        else er[r * 8 + (l32 - 8)] = acc4[reg];
      }
    }
  }
}

// ---------------- CSR build
__global__ void deg_count(const int* __restrict__ dst, int* __restrict__ deg, int E) {
  int i = blockIdx.x * blockDim.x + threadIdx.x;
  if (i < E) atomicAdd(&deg[dst[i]], 1);
}

__global__ __launch_bounds__(256) void scan1(const int* __restrict__ deg, int* __restrict__ offs,
                                             int* __restrict__ bsums, int n) {
  __shared__ int sh[256];
  int i = blockIdx.x * 256 + threadIdx.x;
  int v = (i < n) ? deg[i] : 0;
  sh[threadIdx.x] = v;
  __syncthreads();
  for (int d = 1; d < 256; d <<= 1) {
    int t = (threadIdx.x >= d) ? sh[threadIdx.x - d] : 0;
    __syncthreads();
    sh[threadIdx.x] += t;
    __syncthreads();
  }
  if (i < n) offs[i + 1] = sh[threadIdx.x];
  if (threadIdx.x == 255) bsums[blockIdx.x] = sh[255];
  if (i == 0) offs[0] = 0;
}

__global__ __launch_bounds__(256) void scan2(int* __restrict__ bsums, int nb) {
  __shared__ int sh[256];
  int t = threadIdx.x;
  int v = (t < nb) ? bsums[t] : 0;
  sh[t] = v;
  __syncthreads();
  for (int d = 1; d < 256; d <<= 1) {
    int tmp = (t >= d) ? sh[t - d] : 0;
    __syncthreads();
    sh[t] += tmp;
    __syncthreads();
  }
  if (t < nb) bsums[t] = (t == 0) ? 0 : sh[t - 1];
}

__global__ __launch_bounds__(256) void scan3(int* __restrict__ offs, const int* __restrict__ bsums,
                                             int* __restrict__ cursor, int n) {
  int i = blockIdx.x * 256 + threadIdx.x;
  if (i < n) {
    int v = offs[i + 1] + bsums[blockIdx.x];
    offs[i + 1] = v;
    cursor[i + 1] = v;
  }
  if (i == 0) cursor[0] = 0;
}

__global__ void scatter_edges(const int* __restrict__ src, const int* __restrict__ dst,
                              int* __restrict__ cursor, int* __restrict__ csrc, int E) {
  int i = blockIdx.x * blockDim.x + threadIdx.x;
  if (i < E) {
    int d = dst[i];
    int pos = atomicAdd(&cursor[d], 1);
    csrc[pos] = src[i];
  }
}

// ---------------- GAT aggregation: one wave per dst node; single-pass softmax
// (no max-shift: alpha = exp(e)/sum(exp(e)), identical normalization), fp8 gather.
// Layout: 16 lanes per edge, 4 edges per wave-iteration, 16B (uint4) gather per
// lane. csrc for the whole node is loaded ONCE (deg<=64 fast path) and
// distributed per-iteration via ds_bpermute, removing the csrc link from the
// per-iteration pointer chase. Weighted accumulate uses v_pk_fma_f32.
__global__ __launch_bounds__(256) void gat_agg(const int* __restrict__ offs,
                                               const int* __restrict__ csrc,
                                               const unsigned char* __restrict__ featq,
                                               const float* __restrict__ el,
                                               const float* __restrict__ er,
                                               const float* __restrict__ bias,
                                               const unsigned short* __restrict__ hres,
                                               unsigned short* __restrict__ hout,
                                               float* __restrict__ partial, int N, int E,
                                               int mode) {
  __shared__ float psum[4][272];  // stride-17 blocks (l16*17+k) to dodge bank alias
  const int tid = threadIdx.x;
  const int wave = tid >> 6;
  const int lane = tid & 63;
  const int eg = lane >> 4;    // edge slot 0..3 within the wave
  const int l16 = lane & 15;   // 16-byte feature block index
  const int head = l16 >> 1;   // 32 features per head, 16 per lane
  const float R = 1.442695041f;  // log2(e)
  const int Em1 = E - 1;

  if (mode == 1) {
#pragma unroll
    for (int w = 0; w < 4; ++w) {
      psum[w][tid] = 0.f;
      if (tid < 16) psum[w][256 + tid] = 0.f;
    }
    __syncthreads();
  }

  for (int n = blockIdx.x * 4 + wave; n < N; n += gridDim.x * 4) {
    const int o0 = offs[n];
    const int deg = offs[n + 1] - o0;
    const float er_f = er[n * 8 + head];
    // one load covers all edges of this node when deg <= 64
    const int s_all = csrc[min(o0 + lane, Em1)];

    float wsum = 0.f;
    f32x2 acc[8] = {};
#pragma unroll 2
    for (int j = 0; j < deg; j += 4) {
      const int eidx = j + eg;
      int s = __shfl(s_all, eidx & 63);
      float e = -1e30f;
      if (eidx < deg) {
        if (__builtin_expect(eidx >= 64, 0)) s = csrc[o0 + eidx];  // rare fallback
        float tv = el[s * 8 + head] + er_f;
        e = fmaxf(tv, NEG_SLOPE * tv);  // leaky-relu
      }
      const uint4 f = *(const uint4*)(featq + (size_t)s * 256 + l16 * 16);
      float wgt = __builtin_amdgcn_exp2f(e * R);  // exp(e); 0 for pad lanes
      wsum += wgt;
      f32x2 wgt2;
      wgt2[0] = wgt;
      wgt2[1] = wgt;
      f32x2 p0 = __builtin_amdgcn_cvt_pk_f32_fp8(f.x, false);
      f32x2 p1 = __builtin_amdgcn_cvt_pk_f32_fp8(f.x, true);
      f32x2 p2 = __builtin_amdgcn_cvt_pk_f32_fp8(f.y, false);
      f32x2 p3 = __builtin_amdgcn_cvt_pk_f32_fp8(f.y, true);
      f32x2 p4 = __builtin_amdgcn_cvt_pk_f32_fp8(f.z, false);
      f32x2 p5 = __builtin_amdgcn_cvt_pk_f32_fp8(f.z, true);
      f32x2 p6 = __builtin_amdgcn_cvt_pk_f32_fp8(f.w, false);
      f32x2 p7 = __builtin_amdgcn_cvt_pk_f32_fp8(f.w, true);
      asm("v_pk_fma_f32 %0, %1, %2, %0" : "+v"(acc[0]) : "v"(wgt2), "v"(p0));
      asm("v_pk_fma_f32 %0, %1, %2, %0" : "+v"(acc[1]) : "v"(wgt2), "v"(p1));
      asm("v_pk_fma_f32 %0, %1, %2, %0" : "+v"(acc[2]) : "v"(wgt2), "v"(p2));
      asm("v_pk_fma_f32 %0, %1, %2, %0" : "+v"(acc[3]) : "v"(wgt2), "v"(p3));
      asm("v_pk_fma_f32 %0, %1, %2, %0" : "+v"(acc[4]) : "v"(wgt2), "v"(p4));
      asm("v_pk_fma_f32 %0, %1, %2, %0" : "+v"(acc[5]) : "v"(wgt2), "v"(p5));
      asm("v_pk_fma_f32 %0, %1, %2, %0" : "+v"(acc[6]) : "v"(wgt2), "v"(p6));
      asm("v_pk_fma_f32 %0, %1, %2, %0" : "+v"(acc[7]) : "v"(wgt2), "v"(p7));
    }

    // combine the four 16-lane edge slots
    wsum += __shfl_xor(wsum, 16);
    wsum += __shfl_xor(wsum, 32);
#pragma unroll
    for (int k = 0; k < 8; ++k) {
      acc[k][0] += __shfl_xor(acc[k][0], 16);
      acc[k][1] += __shfl_xor(acc[k][1], 16);
      acc[k][0] += __shfl_xor(acc[k][0], 32);
      acc[k][1] += __shfl_xor(acc[k][1], 32);
    }

    if (lane < 16) {
      const float inv = (wsum > 0.f) ? 1.f / wsum : 0.f;
      float bb[16];
      const float* bp = bias + l16 * 16;
      *(float4*)&bb[0] = *(const float4*)(bp + 0);
      *(float4*)&bb[4] = *(const float4*)(bp + 4);
      *(float4*)&bb[8] = *(const float4*)(bp + 8);
      *(float4*)&bb[12] = *(const float4*)(bp + 12);
      float v[16];
      const float* af = (const float*)acc;
#pragma unroll
      for (int k = 0; k < 16; ++k) v[k] = fmaf(af[k], inv, bb[k]);
      if (hres) {
        const unsigned short* hp = hres + (size_t)n * 256 + l16 * 16;
        short8 r0 = *(const short8*)hp;
        short8 r1 = *(const short8*)(hp + 8);
#pragma unroll
        for (int k = 0; k < 8; ++k) {
          v[k] += b2f((unsigned short)r0[k]);
          v[8 + k] += b2f((unsigned short)r1[k]);
        }
      }
#pragma unroll
      for (int k = 0; k < 16; ++k) v[k] = eluf(v[k]);
      if (mode == 0) {
        short8 o0v, o1v;
#pragma unroll
        for (int k = 0; k < 8; ++k) {
          o0v[k] = (short)f2b(v[k]);
          o1v[k] = (short)f2b(v[8 + k]);
        }
        unsigned short* op = hout + (size_t)n * 256 + l16 * 16;
        *(short8*)op = o0v;
        *(short8*)(op + 8) = o1v;
      } else {
#pragma unroll
        for (int k = 0; k < 16; ++k) psum[wave][l16 * 17 + k] += v[k];
      }
    }
  }

  if (mode == 1) {
    __syncthreads();
    int tt = threadIdx.x;
    int sidx = (tt >> 4) * 17 + (tt & 15);
    partial[(size_t)blockIdx.x * 256 + tt] =
        psum[0][sidx] + psum[1][sidx] + psum[2][sidx] + psum[3][sidx];
  }
}

// ---------------- reduce partial column sums -> s[256]
__global__ __launch_bounds__(256) void reduce_partials(const float* __restrict__ partial,
                                                       float* __restrict__ s, int rows) {
  int t = threadIdx.x;
  float acc = 0.f;
  for (int r = blockIdx.x; r < rows; r += gridDim.x) acc += partial[(size_t)r * 256 + t];
  atomicAdd(&s[t], acc);
}

// ---------------- out[c] = (s/N) @ Wl + bl
__global__ __launch_bounds__(128) void final_linear(const float* __restrict__ s,
                                                    const float* __restrict__ Wl,
                                                    const float* __restrict__ bl,
                                                    float* __restrict__ out, float invN) {
  int c = threadIdx.x;
  float acc = 0.f;
  for (int k = 0; k < 256; ++k) acc = fmaf(s[k], Wl[k * 128 + c], acc);
  out[c] = acc * invN + bl[c];
}

extern "C" void kernel_launch(void* const* d_in, const int* in_sizes, int n_in, void* d_out,
                              int out_size, void* d_ws, size_t ws_size, hipStream_t stream) {
  const float* x  = (const float*)d_in[0];
  const int* src  = (const int*)d_in[1];
  const int* dst  = (const int*)d_in[2];
  const float* W1 = (const float*)d_in[3];
  const float* al1 = (const float*)d_in[4];
  const float* ar1 = (const float*)d_in[5];
  const float* b1 = (const float*)d_in[6];
  const float* W2 = (const float*)d_in[7];
  const float* al2 = (const float*)d_in[8];
  const float* ar2 = (const float*)d_in[9];
  const float* b2 = (const float*)d_in[10];
  const float* Wl = (const float*)d_in[11];
  const float* bl = (const float*)d_in[12];
  float* out = (float*)d_out;

  const int N = in_sizes[0] / 128;  // 50000
  const int E = in_sizes[1];        // 800000
  const int AGG_BLOCKS = 2048;

  // ---- workspace carve (deg and svec adjacent -> one memset)
  char* w = (char*)d_ws;
  unsigned char* featq = (unsigned char*)w;   w += (size_t)N * 256;      // 12.8 MB fp8
  unsigned short* h1b  = (unsigned short*)w;  w += (size_t)N * 256 * 2;  // 25.6 MB bf16
  unsigned short* B1t  = (unsigned short*)w;  w += (size_t)288 * 128 * 2;
  unsigned short* B2t  = (unsigned short*)w;  w += (size_t)288 * 256 * 2;
  float* el = (float*)w;        w += (size_t)N * 8 * 4;
  float* er = (float*)w;        w += (size_t)N * 8 * 4;
  int* offs = (int*)w;          w += (size_t)(N + 64) * 4;
  int* deg = (int*)w;           w += (size_t)N * 4;
  float* svec = (float*)w;      w += 256 * 4;
  int* cursor = (int*)w;        w += (size_t)(N + 64) * 4;
  int* csrc = (int*)w;          w += (size_t)E * 4;
  int* bsums = (int*)w;         w += 256 * 4;
  float* partial = (float*)w;   w += (size_t)AGG_BLOCKS * 256 * 4;

  const int nb = (N + 255) / 256;
  const int eb = (E + 255) / 256;
  const int gmb = (N + GBM - 1) / GBM;  // 782

  // ---- CSR build (dst-indexed); deg+svec zeroed in one memset
  hipMemsetAsync(deg, 0, (size_t)(N + 256) * 4, stream);
  deg_count<<<eb, 256, 0, stream>>>(dst, deg, E);
  scan1<<<nb, 256, 0, stream>>>(deg, offs, bsums, N);
  scan2<<<1, 256, 0, stream>>>(bsums, nb);
  scan3<<<nb, 256, 0, stream>>>(offs, bsums, cursor, N);
  scatter_edges<<<eb, 256, 0, stream>>>(src, dst, cursor, csrc, E);

  // ---- weight casts + P (el/er projection) build
  cast_w_both<<<432, 256, 0, stream>>>(W1, B1t, W2, B2t, al1, ar1, al2, ar2);

  // ---- layer 1 (A = x fp32; feat -> fp8; el/er from epilogue)
  gemm_bf16_v4<<<gmb, 256, 0, stream>>>(x, 1, B1t, featq, el, er, N, 128);
  gat_agg<<<AGG_BLOCKS, 256, 0, stream>>>(offs, csrc, featq, el, er, b1, nullptr, h1b, nullptr, N, E, 0);

  // ---- layer 2
  gemm_bf16_v4<<<gmb, 256, 0, stream>>>(h1b, 0, B2t, featq, el, er, N, 256);
  gat_agg<<<AGG_BLOCKS, 256, 0, stream>>>(offs, csrc, featq, el, er, b2, h1b, nullptr, partial, N, E, 1);

  // ---- mean over nodes, then final linear
  reduce_partials<<<64, 256, 0, stream>>>(partial, svec, AGG_BLOCKS);
  final_linear<<<1, 128, 0, stream>>>(svec, Wl, bl, out, 1.0f / (float)N);
}

// Round 2
// 407.311 us; speedup vs baseline: 1.0348x; 1.0348x over previous
//
#include <hip/hip_runtime.h>
#include <math.h>

#define NEG_SLOPE 0.2f

typedef __attribute__((ext_vector_type(8))) short short8;
typedef __attribute__((ext_vector_type(2))) float f32x2;
typedef __attribute__((ext_vector_type(4))) float f32x4;
typedef __attribute__((ext_vector_type(16))) float f32x16;

__device__ __forceinline__ float eluf(float x) { return x > 0.f ? x : expm1f(x); }
__device__ __forceinline__ unsigned short f2b(float f) {
  unsigned int u = __float_as_uint(f);
  u += 0x7FFFu + ((u >> 16) & 1u);  // RNE
  return (unsigned short)(u >> 16);
}
__device__ __forceinline__ float b2f(unsigned short h) {
  return __uint_as_float(((unsigned int)h) << 16);
}

// ---------------- weights: build extended Bt for both layers.
// B1t[288][128]: rows 0..255 = W1^T bf16; rows 256..263 = P_el (W1 . al1),
// rows 264..271 = P_er, rows 272..287 = 0.   B2t[288][256] likewise.
__global__ __launch_bounds__(256) void cast_w_both(const float* __restrict__ W1,
                                                   unsigned short* __restrict__ B1t,
                                                   const float* __restrict__ W2,
                                                   unsigned short* __restrict__ B2t,
                                                   const float* __restrict__ al1,
                                                   const float* __restrict__ ar1,
                                                   const float* __restrict__ al2,
                                                   const float* __restrict__ ar2) {
  int id = blockIdx.x * 256 + threadIdx.x;
  if (id < 128 * 256) {
    int k = id >> 8, n = id & 255;
    B1t[(size_t)n * 128 + k] = f2b(W1[id]);
    return;
  }
  id -= 128 * 256;
  if (id < 256 * 256) {
    int k = id >> 8, n = id & 255;
    B2t[(size_t)n * 256 + k] = f2b(W2[id]);
    return;
  }
  id -= 256 * 256;
  if (id < 128 * 16) {
    int k = id >> 4, h2 = id & 15;
    int h = h2 & 7;
    const float* av = (h2 < 8) ? al1 : ar1;
    float acc = 0.f;
    for (int d = 0; d < 32; ++d) acc = fmaf(W1[(size_t)k * 256 + h * 32 + d], av[h * 32 + d], acc);
    B1t[(size_t)(256 + h2) * 128 + k] = f2b(acc);
    return;
  }
  id -= 128 * 16;
  if (id < 256 * 16) {
    int k = id >> 4, h2 = id & 15;
    int h = h2 & 7;
    const float* av = (h2 < 8) ? al2 : ar2;
    float acc = 0.f;
    for (int d = 0; d < 32; ++d) acc = fmaf(W2[(size_t)k * 256 + h * 32 + d], av[h * 32 + d], acc);
    B2t[(size_t)(256 + h2) * 256 + k] = f2b(acc);
    return;
  }
  id -= 256 * 16;
  if (id < 16 * 128) {
    int k = id & 127, rr = 272 + (id >> 7);
    B1t[(size_t)rr * 128 + k] = 0;
    return;
  }
  id -= 16 * 128;
  if (id < 16 * 256) {
    int k = id & 255, rr = 272 + (id >> 8);
    B2t[(size_t)rr * 256 + k] = 0;
  }
}

// ---------------- GEMM: Cq[M][256] (fp8 e4m3) = A[M][K] @ B  (Bt[288][K] bf16).
// BM=64 x BN=256(+32 el/er cols), BK=32, 4 waves 2x2, 32x32x16 MFMA.
#define GBM 64
#define GBK 32
#define GLDK 36
__global__ __launch_bounds__(256) void gemm_bf16_v4(const void* __restrict__ Araw, int a_fp32,
                                                    const unsigned short* __restrict__ Bt,
                                                    unsigned char* __restrict__ Cq,
                                                    float* __restrict__ el, float* __restrict__ er,
                                                    int M, int K) {
  __shared__ unsigned short As[GBM][GLDK];
  __shared__ unsigned short Bs[288][GLDK];
  const int tid = threadIdx.x;
  const int wave = tid >> 6, lane = tid & 63;
  const int wm = wave >> 1, wn = wave & 1;
  const int l32 = lane & 31, lhalf = lane >> 5;
  const int row0 = blockIdx.x * GBM;

  f32x16 acc[4] = {};
  f32x16 acc4 = {};

  const int ar = tid >> 2;
  const int ac = (tid & 3) * 8;
  const bool arow_ok = (row0 + ar) < M;

  for (int kk = 0; kk < K; kk += GBK) {
    short8 av = {};
    if (arow_ok) {
      if (a_fp32) {
        const float* p = (const float*)Araw + (size_t)(row0 + ar) * K + kk + ac;
        float4 lo = *(const float4*)p;
        float4 hi = *(const float4*)(p + 4);
        av[0] = (short)f2b(lo.x); av[1] = (short)f2b(lo.y);
        av[2] = (short)f2b(lo.z); av[3] = (short)f2b(lo.w);
        av[4] = (short)f2b(hi.x); av[5] = (short)f2b(hi.y);
        av[6] = (short)f2b(hi.z); av[7] = (short)f2b(hi.w);
      } else {
        av = *(const short8*)((const unsigned short*)Araw + (size_t)(row0 + ar) * K + kk + ac);
      }
    }
    *(short8*)&As[ar][ac] = av;
    {
      const unsigned short* bp = Bt + (size_t)tid * K + kk;
      short8 b0 = *(const short8*)(bp + 0);
      short8 b1 = *(const short8*)(bp + 8);
      short8 b2 = *(const short8*)(bp + 16);
      short8 b3 = *(const short8*)(bp + 24);
      *(short8*)&Bs[tid][0] = b0;
      *(short8*)&Bs[tid][8] = b1;
      *(short8*)&Bs[tid][16] = b2;
      *(short8*)&Bs[tid][24] = b3;
    }
    if (tid < 32) {
      const unsigned short* bp = Bt + (size_t)(256 + tid) * K + kk;
      short8 b0 = *(const short8*)(bp + 0);
      short8 b1 = *(const short8*)(bp + 8);
      short8 b2 = *(const short8*)(bp + 16);
      short8 b3 = *(const short8*)(bp + 24);
      *(short8*)&Bs[256 + tid][0] = b0;
      *(short8*)&Bs[256 + tid][8] = b1;
      *(short8*)&Bs[256 + tid][16] = b2;
      *(short8*)&Bs[256 + tid][24] = b3;
    }
    __syncthreads();
#pragma unroll
    for (int s = 0; s < 2; ++s) {
      short8 af = *(short8*)&As[wm * 32 + l32][s * 16 + lhalf * 8];
#pragma unroll
      for (int t = 0; t < 4; ++t) {
        short8 bf = *(short8*)&Bs[wn * 128 + t * 32 + l32][s * 16 + lhalf * 8];
        acc[t] = __builtin_amdgcn_mfma_f32_32x32x16_bf16(af, bf, acc[t], 0, 0, 0);
      }
      if (wn == 1) {
        short8 bf = *(short8*)&Bs[256 + l32][s * 16 + lhalf * 8];
        acc4 = __builtin_amdgcn_mfma_f32_32x32x16_bf16(af, bf, acc4, 0, 0, 0);
      }
    }
    __syncthreads();
  }

#pragma unroll
  for (int t = 0; t < 4; ++t) {
    int col = wn * 128 + t * 32 + l32;
#pragma unroll
    for (int reg = 0; reg < 16; ++reg) {
      int row = wm * 32 + (reg & 3) + 8 * (reg >> 2) + 4 * lhalf;
      int r = row0 + row;
      if (r < M) {
        int pk = __builtin_amdgcn_cvt_pk_fp8_f32(acc[t][reg], acc[t][reg], 0, false);
        Cq[(size_t)r * 256 + col] = (unsigned char)(pk & 0xFF);
      }
    }
  }
  if (wn == 1 && l32 < 16) {
#pragma unroll
    for (int reg = 0; reg < 16; ++reg) {
      int row = wm * 32 + (reg & 3) + 8 * (reg >> 2) + 4 * lhalf;
      int r = row0 + row;
      if (r < M) {
        if (l32 < 8) el[r * 8 + l32] = acc4[reg];
        else er[r * 8 + (l32 - 8)] = acc4[reg];
      }
    }
  }
}

// ---------------- CSR build
__global__ void deg_count(const int* __restrict__ dst, int* __restrict__ deg, int E) {
  int i = blockIdx.x * blockDim.x + threadIdx.x;
  if (i < E) atomicAdd(&deg[dst[i]], 1);
}

__global__ __launch_bounds__(256) void scan1(const int* __restrict__ deg, int* __restrict__ offs,
                                             int* __restrict__ bsums, int n) {
  __shared__ int sh[256];
  int i = blockIdx.x * 256 + threadIdx.x;
  int v = (i < n) ? deg[i] : 0;
  sh[threadIdx.x] = v;
  __syncthreads();
  for (int d = 1; d < 256; d <<= 1) {
    int t = (threadIdx.x >= d) ? sh[threadIdx.x - d] : 0;
    __syncthreads();
    sh[threadIdx.x] += t;
    __syncthreads();
  }
  if (i < n) offs[i + 1] = sh[threadIdx.x];
  if (threadIdx.x == 255) bsums[blockIdx.x] = sh[255];
  if (i == 0) offs[0] = 0;
}

__global__ __launch_bounds__(256) void scan2(int* __restrict__ bsums, int nb) {
  __shared__ int sh[256];
  int t = threadIdx.x;
  int v = (t < nb) ? bsums[t] : 0;
  sh[t] = v;
  __syncthreads();
  for (int d = 1; d < 256; d <<= 1) {
    int tmp = (t >= d) ? sh[t - d] : 0;
    __syncthreads();
    sh[t] += tmp;
    __syncthreads();
  }
  if (t < nb) bsums[t] = (t == 0) ? 0 : sh[t - 1];
}

__global__ __launch_bounds__(256) void scan3(int* __restrict__ offs, const int* __restrict__ bsums,
                                             int* __restrict__ cursor, int n) {
  int i = blockIdx.x * 256 + threadIdx.x;
  if (i < n) {
    int v = offs[i + 1] + bsums[blockIdx.x];
    offs[i + 1] = v;
    cursor[i + 1] = v;
  }
  if (i == 0) cursor[0] = 0;
}

__global__ void scatter_edges(const int* __restrict__ src, const int* __restrict__ dst,
                              int* __restrict__ cursor, int* __restrict__ csrc, int E) {
  int i = blockIdx.x * blockDim.x + threadIdx.x;
  if (i < E) {
    int d = dst[i];
    int pos = atomicAdd(&cursor[d], 1);
    csrc[pos] = src[i];
  }
}

// ---------------- GAT aggregation: one wave per dst node; single-pass softmax
// (no max-shift: alpha = exp(e)/sum(exp(e)), identical normalization), fp8 gather.
// Round-0 structure (32 lanes/edge, edge-pair per wave step); this revision only
// deepens the unroll (4 pairs = 8 edges in flight) and packs the accumulate
// with v_pk_fma_f32. __launch_bounds__(256,8) caps VGPR at 64 so the unroll
// cannot drop the occupancy tier.
__global__ __launch_bounds__(256, 8) void gat_agg(const int* __restrict__ offs,
                                                  const int* __restrict__ csrc,
                                                  const unsigned char* __restrict__ featq,
                                                  const float* __restrict__ el,
                                                  const float* __restrict__ er,
                                                  const float* __restrict__ bias,
                                                  const unsigned short* __restrict__ hres,
                                                  unsigned short* __restrict__ hout,
                                                  float* __restrict__ partial, int N, int mode) {
  __shared__ float psum[4][256];
  const int wave = threadIdx.x >> 6;
  const int lane = threadIdx.x & 63;
  const int epair = lane >> 5;  // which edge of the pair
  const int l32 = lane & 31;    // feature block l32*8 .. +7
  const int fh = l32 >> 2;      // head of my feature block
  const float R = 1.442695041f; // log2(e)

  float bv[8];
  {
    float4 blo = *(const float4*)(bias + l32 * 8);
    float4 bhi = *(const float4*)(bias + l32 * 8 + 4);
    bv[0] = blo.x; bv[1] = blo.y; bv[2] = blo.z; bv[3] = blo.w;
    bv[4] = bhi.x; bv[5] = bhi.y; bv[6] = bhi.z; bv[7] = bhi.w;
  }
  float t[8] = {};

  for (int n = blockIdx.x * 4 + wave; n < N; n += gridDim.x * 4) {
    const int o0 = offs[n];
    const int deg = offs[n + 1] - o0;
    const float er_f = er[n * 8 + fh];

    float wsum = 0.f;
    f32x2 acc[4] = {};
#pragma unroll 4
    for (int j = 0; j < deg; j += 2) {
      int eidx = j + epair;
      int s = 0;
      float e = -1e30f;
      if (eidx < deg) {
        s = csrc[o0 + eidx];
        float tv = el[s * 8 + fh] + er_f;
        e = fmaxf(tv, NEG_SLOPE * tv);  // leaky-relu
      }
      float wgt = __builtin_amdgcn_exp2f(e * R);  // exp(e); 0 for pad lanes
      wsum += wgt;
      f32x2 wgt2;
      wgt2[0] = wgt;
      wgt2[1] = wgt;
      uint2 f = *(const uint2*)(featq + (size_t)s * 256 + l32 * 8);
      f32x2 p0 = __builtin_amdgcn_cvt_pk_f32_fp8(f.x, false);
      f32x2 p1 = __builtin_amdgcn_cvt_pk_f32_fp8(f.x, true);
      f32x2 p2 = __builtin_amdgcn_cvt_pk_f32_fp8(f.y, false);
      f32x2 p3 = __builtin_amdgcn_cvt_pk_f32_fp8(f.y, true);
      asm("v_pk_fma_f32 %0, %1, %2, %0" : "+v"(acc[0]) : "v"(wgt2), "v"(p0));
      asm("v_pk_fma_f32 %0, %1, %2, %0" : "+v"(acc[1]) : "v"(wgt2), "v"(p1));
      asm("v_pk_fma_f32 %0, %1, %2, %0" : "+v"(acc[2]) : "v"(wgt2), "v"(p2));
      asm("v_pk_fma_f32 %0, %1, %2, %0" : "+v"(acc[3]) : "v"(wgt2), "v"(p3));
    }

    // combine the two 32-lane halves
    wsum += __shfl_xor(wsum, 32);
#pragma unroll
    for (int k = 0; k < 4; ++k) {
      acc[k][0] += __shfl_xor(acc[k][0], 32);
      acc[k][1] += __shfl_xor(acc[k][1], 32);
    }

    if (lane < 32) {
      float inv = (wsum > 0.f) ? 1.f / wsum : 0.f;
      const float* af = (const float*)acc;
      float v[8];
#pragma unroll
      for (int k = 0; k < 8; ++k) v[k] = fmaf(af[k], inv, bv[k]);
      if (hres) {
        short8 r8 = *(const short8*)(hres + (size_t)n * 256 + l32 * 8);
#pragma unroll
        for (int k = 0; k < 8; ++k) v[k] += b2f((unsigned short)r8[k]);
      }
#pragma unroll
      for (int k = 0; k < 8; ++k) v[k] = eluf(v[k]);
      if (mode == 0) {
        short8 o;
#pragma unroll
        for (int k = 0; k < 8; ++k) o[k] = (short)f2b(v[k]);
        *(short8*)(hout + (size_t)n * 256 + l32 * 8) = o;
      } else {
#pragma unroll
        for (int k = 0; k < 8; ++k) t[k] += v[k];
      }
    }
  }

  if (mode == 1) {
    if (lane < 32) {
#pragma unroll
      for (int k = 0; k < 8; ++k) psum[wave][l32 * 8 + k] = t[k];
    }
    __syncthreads();
    int tt = threadIdx.x;
    partial[(size_t)blockIdx.x * 256 + tt] =
        psum[0][tt] + psum[1][tt] + psum[2][tt] + psum[3][tt];
  }
}

// ---------------- reduce partial column sums -> s[256]
__global__ __launch_bounds__(256) void reduce_partials(const float* __restrict__ partial,
                                                       float* __restrict__ s, int rows) {
  int t = threadIdx.x;
  float acc = 0.f;
  for (int r = blockIdx.x; r < rows; r += gridDim.x) acc += partial[(size_t)r * 256 + t];
  atomicAdd(&s[t], acc);
}

// ---------------- out[c] = (s/N) @ Wl + bl
__global__ __launch_bounds__(128) void final_linear(const float* __restrict__ s,
                                                    const float* __restrict__ Wl,
                                                    const float* __restrict__ bl,
                                                    float* __restrict__ out, float invN) {
  int c = threadIdx.x;
  float acc = 0.f;
  for (int k = 0; k < 256; ++k) acc = fmaf(s[k], Wl[k * 128 + c], acc);
  out[c] = acc * invN + bl[c];
}

extern "C" void kernel_launch(void* const* d_in, const int* in_sizes, int n_in, void* d_out,
                              int out_size, void* d_ws, size_t ws_size, hipStream_t stream) {
  const float* x  = (const float*)d_in[0];
  const int* src  = (const int*)d_in[1];
  const int* dst  = (const int*)d_in[2];
  const float* W1 = (const float*)d_in[3];
  const float* al1 = (const float*)d_in[4];
  const float* ar1 = (const float*)d_in[5];
  const float* b1 = (const float*)d_in[6];
  const float* W2 = (const float*)d_in[7];
  const float* al2 = (const float*)d_in[8];
  const float* ar2 = (const float*)d_in[9];
  const float* b2 = (const float*)d_in[10];
  const float* Wl = (const float*)d_in[11];
  const float* bl = (const float*)d_in[12];
  float* out = (float*)d_out;

  const int N = in_sizes[0] / 128;  // 50000
  const int E = in_sizes[1];        // 800000
  const int AGG_BLOCKS = 2048;

  // ---- workspace carve (deg and svec adjacent -> one memset)
  char* w = (char*)d_ws;
  unsigned char* featq = (unsigned char*)w;   w += (size_t)N * 256;      // 12.8 MB fp8
  unsigned short* h1b  = (unsigned short*)w;  w += (size_t)N * 256 * 2;  // 25.6 MB bf16
  unsigned short* B1t  = (unsigned short*)w;  w += (size_t)288 * 128 * 2;
  unsigned short* B2t  = (unsigned short*)w;  w += (size_t)288 * 256 * 2;
  float* el = (float*)w;        w += (size_t)N * 8 * 4;
  float* er = (float*)w;        w += (size_t)N * 8 * 4;
  int* offs = (int*)w;          w += (size_t)(N + 64) * 4;
  int* deg = (int*)w;           w += (size_t)N * 4;
  float* svec = (float*)w;      w += 256 * 4;
  int* cursor = (int*)w;        w += (size_t)(N + 64) * 4;
  int* csrc = (int*)w;          w += (size_t)E * 4;
  int* bsums = (int*)w;         w += 256 * 4;
  float* partial = (float*)w;   w += (size_t)AGG_BLOCKS * 256 * 4;

  const int nb = (N + 255) / 256;
  const int eb = (E + 255) / 256;
  const int gmb = (N + GBM - 1) / GBM;  // 782

  // ---- CSR build (dst-indexed); deg+svec zeroed in one memset
  hipMemsetAsync(deg, 0, (size_t)(N + 256) * 4, stream);
  deg_count<<<eb, 256, 0, stream>>>(dst, deg, E);
  scan1<<<nb, 256, 0, stream>>>(deg, offs, bsums, N);
  scan2<<<1, 256, 0, stream>>>(bsums, nb);
  scan3<<<nb, 256, 0, stream>>>(offs, bsums, cursor, N);
  scatter_edges<<<eb, 256, 0, stream>>>(src, dst, cursor, csrc, E);

  // ---- weight casts + P (el/er projection) build
  cast_w_both<<<432, 256, 0, stream>>>(W1, B1t, W2, B2t, al1, ar1, al2, ar2);

  // ---- layer 1 (A = x fp32; feat -> fp8; el/er from epilogue)
  gemm_bf16_v4<<<gmb, 256, 0, stream>>>(x, 1, B1t, featq, el, er, N, 128);
  gat_agg<<<AGG_BLOCKS, 256, 0, stream>>>(offs, csrc, featq, el, er, b1, nullptr, h1b, nullptr, N, 0);

  // ---- layer 2
  gemm_bf16_v4<<<gmb, 256, 0, stream>>>(h1b, 0, B2t, featq, el, er, N, 256);
  gat_agg<<<AGG_BLOCKS, 256, 0, stream>>>(offs, csrc, featq, el, er, b2, h1b, nullptr, partial, N, 1);

  // ---- mean over nodes, then final linear
  reduce_partials<<<64, 256, 0, stream>>>(partial, svec, AGG_BLOCKS);
  final_linear<<<1, 128, 0, stream>>>(svec, Wl, bl, out, 1.0f / (float)N);
}

// Round 3
// 368.029 us; speedup vs baseline: 1.1452x; 1.1067x over previous
//
#include <hip/hip_runtime.h>
#include <math.h>

#define NEG_SLOPE 0.2f

typedef __attribute__((ext_vector_type(8))) short short8;
typedef __attribute__((ext_vector_type(2))) float f32x2;
typedef __attribute__((ext_vector_type(4))) float f32x4;
typedef __attribute__((ext_vector_type(16))) float f32x16;

__device__ __forceinline__ float eluf(float x) { return x > 0.f ? x : expm1f(x); }
__device__ __forceinline__ unsigned short f2b(float f) {
  unsigned int u = __float_as_uint(f);
  u += 0x7FFFu + ((u >> 16) & 1u);  // RNE
  return (unsigned short)(u >> 16);
}
__device__ __forceinline__ float b2f(unsigned short h) {
  return __uint_as_float(((unsigned int)h) << 16);
}

// ---------------- weights: build extended Bt for both layers.
// B1t[288][128]: rows 0..255 = W1^T bf16; rows 256..263 = P_el (W1 . al1),
// rows 264..271 = P_er, rows 272..287 = 0.   B2t[288][256] likewise.
__global__ __launch_bounds__(256) void cast_w_both(const float* __restrict__ W1,
                                                   unsigned short* __restrict__ B1t,
                                                   const float* __restrict__ W2,
                                                   unsigned short* __restrict__ B2t,
                                                   const float* __restrict__ al1,
                                                   const float* __restrict__ ar1,
                                                   const float* __restrict__ al2,
                                                   const float* __restrict__ ar2) {
  int id = blockIdx.x * 256 + threadIdx.x;
  if (id < 128 * 256) {
    int k = id >> 8, n = id & 255;
    B1t[(size_t)n * 128 + k] = f2b(W1[id]);
    return;
  }
  id -= 128 * 256;
  if (id < 256 * 256) {
    int k = id >> 8, n = id & 255;
    B2t[(size_t)n * 256 + k] = f2b(W2[id]);
    return;
  }
  id -= 256 * 256;
  if (id < 128 * 16) {
    int k = id >> 4, h2 = id & 15;
    int h = h2 & 7;
    const float* av = (h2 < 8) ? al1 : ar1;
    float acc = 0.f;
    for (int d = 0; d < 32; ++d) acc = fmaf(W1[(size_t)k * 256 + h * 32 + d], av[h * 32 + d], acc);
    B1t[(size_t)(256 + h2) * 128 + k] = f2b(acc);
    return;
  }
  id -= 128 * 16;
  if (id < 256 * 16) {
    int k = id >> 4, h2 = id & 15;
    int h = h2 & 7;
    const float* av = (h2 < 8) ? al2 : ar2;
    float acc = 0.f;
    for (int d = 0; d < 32; ++d) acc = fmaf(W2[(size_t)k * 256 + h * 32 + d], av[h * 32 + d], acc);
    B2t[(size_t)(256 + h2) * 256 + k] = f2b(acc);
    return;
  }
  id -= 256 * 16;
  if (id < 16 * 128) {
    int k = id & 127, rr = 272 + (id >> 7);
    B1t[(size_t)rr * 128 + k] = 0;
    return;
  }
  id -= 16 * 128;
  if (id < 16 * 256) {
    int k = id & 255, rr = 272 + (id >> 8);
    B2t[(size_t)rr * 256 + k] = 0;
  }
}

// ---------------- GEMM: Cq[M][256] (fp8 e4m3) = A[M][K] @ B  (Bt[288][K] bf16).
// BM=64 x BN=256(+32 el/er cols), BK=32, 4 waves 2x2, 32x32x16 MFMA.
#define GBM 64
#define GBK 32
#define GLDK 36
__global__ __launch_bounds__(256) void gemm_bf16_v4(const void* __restrict__ Araw, int a_fp32,
                                                    const unsigned short* __restrict__ Bt,
                                                    unsigned char* __restrict__ Cq,
                                                    float* __restrict__ el, float* __restrict__ er,
                                                    int M, int K) {
  __shared__ unsigned short As[GBM][GLDK];
  __shared__ unsigned short Bs[288][GLDK];
  const int tid = threadIdx.x;
  const int wave = tid >> 6, lane = tid & 63;
  const int wm = wave >> 1, wn = wave & 1;
  const int l32 = lane & 31, lhalf = lane >> 5;
  const int row0 = blockIdx.x * GBM;

  f32x16 acc[4] = {};
  f32x16 acc4 = {};

  const int ar = tid >> 2;
  const int ac = (tid & 3) * 8;
  const bool arow_ok = (row0 + ar) < M;

  for (int kk = 0; kk < K; kk += GBK) {
    short8 av = {};
    if (arow_ok) {
      if (a_fp32) {
        const float* p = (const float*)Araw + (size_t)(row0 + ar) * K + kk + ac;
        float4 lo = *(const float4*)p;
        float4 hi = *(const float4*)(p + 4);
        av[0] = (short)f2b(lo.x); av[1] = (short)f2b(lo.y);
        av[2] = (short)f2b(lo.z); av[3] = (short)f2b(lo.w);
        av[4] = (short)f2b(hi.x); av[5] = (short)f2b(hi.y);
        av[6] = (short)f2b(hi.z); av[7] = (short)f2b(hi.w);
      } else {
        av = *(const short8*)((const unsigned short*)Araw + (size_t)(row0 + ar) * K + kk + ac);
      }
    }
    *(short8*)&As[ar][ac] = av;
    {
      const unsigned short* bp = Bt + (size_t)tid * K + kk;
      short8 b0 = *(const short8*)(bp + 0);
      short8 b1 = *(const short8*)(bp + 8);
      short8 b2 = *(const short8*)(bp + 16);
      short8 b3 = *(const short8*)(bp + 24);
      *(short8*)&Bs[tid][0] = b0;
      *(short8*)&Bs[tid][8] = b1;
      *(short8*)&Bs[tid][16] = b2;
      *(short8*)&Bs[tid][24] = b3;
    }
    if (tid < 32) {
      const unsigned short* bp = Bt + (size_t)(256 + tid) * K + kk;
      short8 b0 = *(const short8*)(bp + 0);
      short8 b1 = *(const short8*)(bp + 8);
      short8 b2 = *(const short8*)(bp + 16);
      short8 b3 = *(const short8*)(bp + 24);
      *(short8*)&Bs[256 + tid][0] = b0;
      *(short8*)&Bs[256 + tid][8] = b1;
      *(short8*)&Bs[256 + tid][16] = b2;
      *(short8*)&Bs[256 + tid][24] = b3;
    }
    __syncthreads();
#pragma unroll
    for (int s = 0; s < 2; ++s) {
      short8 af = *(short8*)&As[wm * 32 + l32][s * 16 + lhalf * 8];
#pragma unroll
      for (int t = 0; t < 4; ++t) {
        short8 bf = *(short8*)&Bs[wn * 128 + t * 32 + l32][s * 16 + lhalf * 8];
        acc[t] = __builtin_amdgcn_mfma_f32_32x32x16_bf16(af, bf, acc[t], 0, 0, 0);
      }
      if (wn == 1) {
        short8 bf = *(short8*)&Bs[256 + l32][s * 16 + lhalf * 8];
        acc4 = __builtin_amdgcn_mfma_f32_32x32x16_bf16(af, bf, acc4, 0, 0, 0);
      }
    }
    __syncthreads();
  }

#pragma unroll
  for (int t = 0; t < 4; ++t) {
    int col = wn * 128 + t * 32 + l32;
#pragma unroll
    for (int reg = 0; reg < 16; ++reg) {
      int row = wm * 32 + (reg & 3) + 8 * (reg >> 2) + 4 * lhalf;
      int r = row0 + row;
      if (r < M) {
        int pk = __builtin_amdgcn_cvt_pk_fp8_f32(acc[t][reg], acc[t][reg], 0, false);
        Cq[(size_t)r * 256 + col] = (unsigned char)(pk & 0xFF);
      }
    }
  }
  if (wn == 1 && l32 < 16) {
#pragma unroll
    for (int reg = 0; reg < 16; ++reg) {
      int row = wm * 32 + (reg & 3) + 8 * (reg >> 2) + 4 * lhalf;
      int r = row0 + row;
      if (r < M) {
        if (l32 < 8) el[r * 8 + l32] = acc4[reg];
        else er[r * 8 + (l32 - 8)] = acc4[reg];
      }
    }
  }
}

// ---------------- CSR build
__global__ void deg_count(const int* __restrict__ dst, int* __restrict__ deg, int E) {
  int i = blockIdx.x * blockDim.x + threadIdx.x;
  if (i < E) atomicAdd(&deg[dst[i]], 1);
}

__global__ __launch_bounds__(256) void scan1(const int* __restrict__ deg, int* __restrict__ offs,
                                             int* __restrict__ bsums, int n) {
  __shared__ int sh[256];
  int i = blockIdx.x * 256 + threadIdx.x;
  int v = (i < n) ? deg[i] : 0;
  sh[threadIdx.x] = v;
  __syncthreads();
  for (int d = 1; d < 256; d <<= 1) {
    int t = (threadIdx.x >= d) ? sh[threadIdx.x - d] : 0;
    __syncthreads();
    sh[threadIdx.x] += t;
    __syncthreads();
  }
  if (i < n) offs[i + 1] = sh[threadIdx.x];
  if (threadIdx.x == 255) bsums[blockIdx.x] = sh[255];
  if (i == 0) offs[0] = 0;
}

__global__ __launch_bounds__(256) void scan2(int* __restrict__ bsums, int nb) {
  __shared__ int sh[256];
  int t = threadIdx.x;
  int v = (t < nb) ? bsums[t] : 0;
  sh[t] = v;
  __syncthreads();
  for (int d = 1; d < 256; d <<= 1) {
    int tmp = (t >= d) ? sh[t - d] : 0;
    __syncthreads();
    sh[t] += tmp;
    __syncthreads();
  }
  if (t < nb) bsums[t] = (t == 0) ? 0 : sh[t - 1];
}

__global__ __launch_bounds__(256) void scan3(int* __restrict__ offs, const int* __restrict__ bsums,
                                             int* __restrict__ cursor, int n) {
  int i = blockIdx.x * 256 + threadIdx.x;
  if (i < n) {
    int v = offs[i + 1] + bsums[blockIdx.x];
    offs[i + 1] = v;
    cursor[i + 1] = v;
  }
  if (i == 0) cursor[0] = 0;
}

__global__ void scatter_edges(const int* __restrict__ src, const int* __restrict__ dst,
                              int* __restrict__ cursor, int* __restrict__ csrc, int E) {
  int i = blockIdx.x * blockDim.x + threadIdx.x;
  if (i < E) {
    int d = dst[i];
    int pos = atomicAdd(&cursor[d], 1);
    csrc[pos] = src[i];
  }
}

// ---------------- GAT aggregation: one wave per dst node; single-pass softmax
// (no max-shift: alpha = exp(e)/sum(exp(e)), identical normalization), fp8 gather.
// Round-0 structure (32 lanes/edge, edge-pair per step, scalar fmaf) plus an
// EXPLICIT 3-stage software pipeline in named registers: while consuming step t,
// the el/featq loads for step t+1 and the csrc load for step t+2 are in flight.
// Invalid tail slots clamp s->0 (row 0 stays L1-hot => negligible extra fetch).
__global__ __launch_bounds__(256, 8) void gat_agg(const int* __restrict__ offs,
                                                  const int* __restrict__ csrc,
                                                  const unsigned char* __restrict__ featq,
                                                  const float* __restrict__ el,
                                                  const float* __restrict__ er,
                                                  const float* __restrict__ bias,
                                                  const unsigned short* __restrict__ hres,
                                                  unsigned short* __restrict__ hout,
                                                  float* __restrict__ partial, int N, int E,
                                                  int mode) {
  __shared__ float psum[4][256];
  const int wave = threadIdx.x >> 6;
  const int lane = threadIdx.x & 63;
  const int epair = lane >> 5;  // which edge of the pair
  const int l32 = lane & 31;    // feature block l32*8 .. +7
  const int fh = l32 >> 2;      // head of my feature block
  const float R = 1.442695041f; // log2(e)
  const int Em1 = E - 1;

  float bv[8];
  {
    float4 blo = *(const float4*)(bias + l32 * 8);
    float4 bhi = *(const float4*)(bias + l32 * 8 + 4);
    bv[0] = blo.x; bv[1] = blo.y; bv[2] = blo.z; bv[3] = blo.w;
    bv[4] = bhi.x; bv[5] = bhi.y; bv[6] = bhi.z; bv[7] = bhi.w;
  }
  float t8[8] = {};

  for (int n = blockIdx.x * 4 + wave; n < N; n += gridDim.x * 4) {
    const int o0 = offs[n];
    const int deg = offs[n + 1] - o0;
    const float er_f = er[n * 8 + fh];
    const int steps = (deg + 1) >> 1;

    float wsum = 0.f;
    float acc[8] = {};

    // ---- pipeline prologue ----
    int sA = csrc[min(o0 + epair, Em1)];          // s for step 0
    int sB = csrc[min(o0 + 2 + epair, Em1)];      // s for step 1
    sA = (epair < deg) ? sA : 0;
    float elA = el[sA * 8 + fh];
    uint2 fA = *(const uint2*)(featq + (size_t)sA * 256 + l32 * 8);

    for (int t = 0; t < steps; ++t) {
      // issue csrc for step t+2 (clamped; L1-hot when past the end)
      int sC = csrc[min(o0 + 2 * t + 4 + epair, Em1)];
      // issue el/featq for step t+1 (invalid -> row 0, L1-hot)
      int nidx = 2 * (t + 1) + epair;
      int sBu = (nidx < deg) ? sB : 0;
      float elB = el[sBu * 8 + fh];
      uint2 fB = *(const uint2*)(featq + (size_t)sBu * 256 + l32 * 8);
      // consume step t
      int eidx = 2 * t + epair;
      float tv = elA + er_f;
      float e = (eidx < deg) ? fmaxf(tv, NEG_SLOPE * tv) : -1e30f;
      float wgt = __builtin_amdgcn_exp2f(e * R);  // exp(e); 0 for pad lanes
      wsum += wgt;
      f32x2 p0 = __builtin_amdgcn_cvt_pk_f32_fp8(fA.x, false);
      f32x2 p1 = __builtin_amdgcn_cvt_pk_f32_fp8(fA.x, true);
      f32x2 p2 = __builtin_amdgcn_cvt_pk_f32_fp8(fA.y, false);
      f32x2 p3 = __builtin_amdgcn_cvt_pk_f32_fp8(fA.y, true);
      acc[0] = fmaf(wgt, p0.x, acc[0]);
      acc[1] = fmaf(wgt, p0.y, acc[1]);
      acc[2] = fmaf(wgt, p1.x, acc[2]);
      acc[3] = fmaf(wgt, p1.y, acc[3]);
      acc[4] = fmaf(wgt, p2.x, acc[4]);
      acc[5] = fmaf(wgt, p2.y, acc[5]);
      acc[6] = fmaf(wgt, p3.x, acc[6]);
      acc[7] = fmaf(wgt, p3.y, acc[7]);
      // rotate pipeline registers
      sB = sC;
      elA = elB;
      fA = fB;
    }

    // combine the two 32-lane halves
    wsum += __shfl_xor(wsum, 32);
#pragma unroll
    for (int k = 0; k < 8; ++k) acc[k] += __shfl_xor(acc[k], 32);

    if (lane < 32) {
      float inv = (wsum > 0.f) ? 1.f / wsum : 0.f;
      float v[8];
#pragma unroll
      for (int k = 0; k < 8; ++k) v[k] = fmaf(acc[k], inv, bv[k]);
      if (hres) {
        short8 r8 = *(const short8*)(hres + (size_t)n * 256 + l32 * 8);
#pragma unroll
        for (int k = 0; k < 8; ++k) v[k] += b2f((unsigned short)r8[k]);
      }
#pragma unroll
      for (int k = 0; k < 8; ++k) v[k] = eluf(v[k]);
      if (mode == 0) {
        short8 o;
#pragma unroll
        for (int k = 0; k < 8; ++k) o[k] = (short)f2b(v[k]);
        *(short8*)(hout + (size_t)n * 256 + l32 * 8) = o;
      } else {
#pragma unroll
        for (int k = 0; k < 8; ++k) t8[k] += v[k];
      }
    }
  }

  if (mode == 1) {
    if (lane < 32) {
#pragma unroll
      for (int k = 0; k < 8; ++k) psum[wave][l32 * 8 + k] = t8[k];
    }
    __syncthreads();
    int tt = threadIdx.x;
    partial[(size_t)blockIdx.x * 256 + tt] =
        psum[0][tt] + psum[1][tt] + psum[2][tt] + psum[3][tt];
  }
}

// ---------------- reduce partial column sums -> s[256]
__global__ __launch_bounds__(256) void reduce_partials(const float* __restrict__ partial,
                                                       float* __restrict__ s, int rows) {
  int t = threadIdx.x;
  float acc = 0.f;
  for (int r = blockIdx.x; r < rows; r += gridDim.x) acc += partial[(size_t)r * 256 + t];
  atomicAdd(&s[t], acc);
}

// ---------------- out[c] = (s/N) @ Wl + bl
__global__ __launch_bounds__(128) void final_linear(const float* __restrict__ s,
                                                    const float* __restrict__ Wl,
                                                    const float* __restrict__ bl,
                                                    float* __restrict__ out, float invN) {
  int c = threadIdx.x;
  float acc = 0.f;
  for (int k = 0; k < 256; ++k) acc = fmaf(s[k], Wl[k * 128 + c], acc);
  out[c] = acc * invN + bl[c];
}

extern "C" void kernel_launch(void* const* d_in, const int* in_sizes, int n_in, void* d_out,
                              int out_size, void* d_ws, size_t ws_size, hipStream_t stream) {
  const float* x  = (const float*)d_in[0];
  const int* src  = (const int*)d_in[1];
  const int* dst  = (const int*)d_in[2];
  const float* W1 = (const float*)d_in[3];
  const float* al1 = (const float*)d_in[4];
  const float* ar1 = (const float*)d_in[5];
  const float* b1 = (const float*)d_in[6];
  const float* W2 = (const float*)d_in[7];
  const float* al2 = (const float*)d_in[8];
  const float* ar2 = (const float*)d_in[9];
  const float* b2 = (const float*)d_in[10];
  const float* Wl = (const float*)d_in[11];
  const float* bl = (const float*)d_in[12];
  float* out = (float*)d_out;

  const int N = in_sizes[0] / 128;  // 50000
  const int E = in_sizes[1];        // 800000
  const int AGG_BLOCKS = 2048;

  // ---- workspace carve (deg and svec adjacent -> one memset)
  char* w = (char*)d_ws;
  unsigned char* featq = (unsigned char*)w;   w += (size_t)N * 256;      // 12.8 MB fp8
  unsigned short* h1b  = (unsigned short*)w;  w += (size_t)N * 256 * 2;  // 25.6 MB bf16
  unsigned short* B1t  = (unsigned short*)w;  w += (size_t)288 * 128 * 2;
  unsigned short* B2t  = (unsigned short*)w;  w += (size_t)288 * 256 * 2;
  float* el = (float*)w;        w += (size_t)N * 8 * 4;
  float* er = (float*)w;        w += (size_t)N * 8 * 4;
  int* offs = (int*)w;          w += (size_t)(N + 64) * 4;
  int* deg = (int*)w;           w += (size_t)N * 4;
  float* svec = (float*)w;      w += 256 * 4;
  int* cursor = (int*)w;        w += (size_t)(N + 64) * 4;
  int* csrc = (int*)w;          w += (size_t)E * 4;
  int* bsums = (int*)w;         w += 256 * 4;
  float* partial = (float*)w;   w += (size_t)AGG_BLOCKS * 256 * 4;

  const int nb = (N + 255) / 256;
  const int eb = (E + 255) / 256;
  const int gmb = (N + GBM - 1) / GBM;  // 782

  // ---- CSR build (dst-indexed); deg+svec zeroed in one memset
  hipMemsetAsync(deg, 0, (size_t)(N + 256) * 4, stream);
  deg_count<<<eb, 256, 0, stream>>>(dst, deg, E);
  scan1<<<nb, 256, 0, stream>>>(deg, offs, bsums, N);
  scan2<<<1, 256, 0, stream>>>(bsums, nb);
  scan3<<<nb, 256, 0, stream>>>(offs, bsums, cursor, N);
  scatter_edges<<<eb, 256, 0, stream>>>(src, dst, cursor, csrc, E);

  // ---- weight casts + P (el/er projection) build
  cast_w_both<<<432, 256, 0, stream>>>(W1, B1t, W2, B2t, al1, ar1, al2, ar2);

  // ---- layer 1 (A = x fp32; feat -> fp8; el/er from epilogue)
  gemm_bf16_v4<<<gmb, 256, 0, stream>>>(x, 1, B1t, featq, el, er, N, 128);
  gat_agg<<<AGG_BLOCKS, 256, 0, stream>>>(offs, csrc, featq, el, er, b1, nullptr, h1b, nullptr, N, E, 0);

  // ---- layer 2
  gemm_bf16_v4<<<gmb, 256, 0, stream>>>(h1b, 0, B2t, featq, el, er, N, 256);
  gat_agg<<<AGG_BLOCKS, 256, 0, stream>>>(offs, csrc, featq, el, er, b2, h1b, nullptr, partial, N, E, 1);

  // ---- mean over nodes, then final linear
  reduce_partials<<<64, 256, 0, stream>>>(partial, svec, AGG_BLOCKS);
  final_linear<<<1, 128, 0, stream>>>(svec, Wl, bl, out, 1.0f / (float)N);
}